// Round 3
// baseline (362.158 us; speedup 1.0000x reference)
//
#include <hip/hip_runtime.h>
#include <hip/hip_bf16.h>
#include <math.h>

#define BATCH 128
#define NEUR 54
#define DT 4
#define STEPS 30
#define PDIM 75             // pooled spatial dim
#define K (PDIM * PDIM)     // 5625
#define QK 1408             // quarter-K padded to 22*64; q=3 covers only 1401
#define NQ 4
#define TOT (BATCH * NEUR)  // 6912
#define RTPB 1024

typedef float vf4 __attribute__((ext_vector_type(4)));

// ---------------- Kernel 1 (fused): pool quarter-row into LDS, then partial FC -----
// v2: 512-thread blocks (same 512-block grid, same quarter mapping).
//  - 4 blocks/CU at full 2048 thr/CU: half-width barriers, 4-way pool/FC stagger.
//  - nontemporal x loads: the once-read 184 MB stream no longer evicts fc_w (1.2 MB)
//    from the per-XCD L2s -> FC reads stay L2-resident.
//  - FC: 8 waves x 7 neurons (no idle waves).
// Per-neuron k-summation order (kk = c*64+lane, then 6-level shfl tree) is bitwise
// identical to the round-0 version -> xf_part unchanged.
__global__ __launch_bounds__(512, 8) void poolfc_kernel(const float* __restrict__ x,
                                                        const float* __restrict__ fc_w,
                                                        float* __restrict__ xf_part) {
    __shared__ float xps[QK];
    int blk = blockIdx.x;
    int b = blk >> 2;
    int q = blk & 3;
    int tid = threadIdx.x;
    int kbase = q * QK;
    int cnt = (q == 3) ? (K - 3 * QK) : QK;  // 1401 or 1408
    const float* xrow = x + (size_t)b * 360000;

    // ---- pool phase: avg_pool2d(x,8) for this quarter -> LDS (tail zeroed) ----
    for (int w = tid; w < QK; w += 512) {
        float s = 0.f;
        if (w < cnt) {
            int gw = kbase + w;
            int i = gw / PDIM;
            int j = gw - i * PDIM;
            const float* base = xrow + (size_t)(i * 8) * 600 + j * 8;
#pragma unroll
            for (int r = 0; r < 8; r++) {
                const vf4* p4 = (const vf4*)(base + r * 600);
                vf4 a = __builtin_nontemporal_load(p4);
                vf4 c = __builtin_nontemporal_load(p4 + 1);
                s += a.x + a.y + a.z + a.w + c.x + c.y + c.z + c.w;
            }
            s *= (1.0f / 64.0f);
        }
        xps[w] = s;
    }
    __syncthreads();

    // ---- FC phase: wave w -> neurons 7w..7w+6, k on lanes (coalesced fc_w reads) ----
    int wid = tid >> 6, lane = tid & 63;
    int nb = wid * 7;
    int cn = NEUR - nb;
    if (cn > 7) cn = 7;  // waves 0..6 -> 7 neurons, wave 7 -> 5

    const float* pw[7];
#pragma unroll
    for (int n = 0; n < 7; n++) {
        int nn = nb + n;
        if (nn > NEUR - 1) nn = NEUR - 1;  // clamp (in-bounds read, store guarded)
        pw[n] = fc_w + (size_t)nn * K + kbase;
    }
    float a[7];
#pragma unroll
    for (int n = 0; n < 7; n++) a[n] = 0.f;

    int full = (cnt == QK) ? (QK / 64) : (QK / 64 - 1);  // unguarded chunks
    for (int c = 0; c < full; c++) {
        int kk = c * 64 + lane;
        float xv = xps[kk];
#pragma unroll
        for (int n = 0; n < 7; n++) a[n] = fmaf(xv, pw[n][kk], a[n]);
    }
    if (cnt != QK) {  // guarded tail chunk (q==3 only)
        int kk = (QK / 64 - 1) * 64 + lane;
        if (kk < cnt) {
            float xv = xps[kk];
#pragma unroll
            for (int n = 0; n < 7; n++) a[n] = fmaf(xv, pw[n][kk], a[n]);
        }
    }
#pragma unroll
    for (int n = 0; n < 7; n++) {
#pragma unroll
        for (int off = 32; off > 0; off >>= 1) a[n] += __shfl_xor(a[n], off, 64);
    }
    if (lane == 0) {
        float* dst = xf_part + (size_t)q * (BATCH * 64) + b * 64 + nb;
#pragma unroll
        for (int n = 0; n < 7; n++)
            if (n < cn) dst[n] = a[n];
    }
}

// ---------------- Kernel 2: 30-step GLM recurrence, single block --------------------
// 8 threads per batch (8*128 = 1024), <=7 neurons/thread.
// Factored-exponential form (verified absmax 0.0 in round 1). Since hist[d] in {0,1}:
//   exp(xf + btl - hsum + hterm) = exp(xf) * exp(btl) * prod_d(1 + hist_d*(e^{hw_d-lw_d}-1))
// Round-1's `#pragma unroll 2` removed (register-pressure regression suspect).
__global__ __launch_bounds__(RTPB) void recurrence_kernel(const float* __restrict__ xf_part,
                                                          const float* __restrict__ fc_b,
                                                          const float* __restrict__ l_weight,
                                                          const float* __restrict__ h_weight,
                                                          float* __restrict__ out) {
    __shared__ float red[2][16];

    int tid = threadIdx.x;
    int b = tid >> 3;
    int sub = tid & 7;
    int n0 = sub * 7;
    int cntn = NEUR - n0; if (cntn > 7) cntn = 7; if (cntn < 0) cntn = 0;  // sub=7 -> 5

    float hw0 = h_weight[0], hw1 = h_weight[1], hw2 = h_weight[2], hw3 = h_weight[3];

    float hist[7][DT];
    float lw[7][DT];
    float gm1[7][DT];   // expm1(hw[d] - lw[j][d])
    float Ebase[7];     // exp(xfv[j])
    float cnt[7], rate[7];

#pragma unroll
    for (int j = 0; j < 7; j++) {
        cnt[j] = 0.f;
#pragma unroll
        for (int d = 0; d < DT; d++) hist[j][d] = 0.f;
        if (j < cntn) {
            int n = n0 + j;
            float xfv = xf_part[b * 64 + n] + xf_part[BATCH * 64 + b * 64 + n] +
                        xf_part[2 * BATCH * 64 + b * 64 + n] +
                        xf_part[3 * BATCH * 64 + b * 64 + n] + fc_b[n];
            float l0 = l_weight[n * DT + 0];
            float l1 = l_weight[n * DT + 1];
            float l2 = l_weight[n * DT + 2];
            float l3 = l_weight[n * DT + 3];
            lw[j][0] = l0; lw[j][1] = l1; lw[j][2] = l2; lw[j][3] = l3;
            gm1[j][0] = expm1f(hw0 - l0);
            gm1[j][1] = expm1f(hw1 - l1);
            gm1[j][2] = expm1f(hw2 - l2);
            gm1[j][3] = expm1f(hw3 - l3);
            Ebase[j] = expf(xfv);
        } else {
#pragma unroll
            for (int d = 0; d < DT; d++) { lw[j][d] = 0.f; gm1[j][d] = 0.f; }
            Ebase[j] = 0.f;
        }
    }

    int wid = tid >> 6;  // 16 waves
    int lane = tid & 63;

    for (int s = 0; s < STEPS; s++) {
        float hsum[7];
        float btl = 0.f;
#pragma unroll
        for (int j = 0; j < 7; j++) {
            hsum[j] = hist[j][0] * lw[j][0] + hist[j][1] * lw[j][1] +
                      hist[j][2] * lw[j][2] + hist[j][3] * lw[j][3];
            btl += hsum[j];
        }
        (void)hsum;  // per-neuron hsum folded into the gm1 product; btl is all we need
#pragma unroll
        for (int off = 4; off > 0; off >>= 1) btl += __shfl_xor(btl, off, 8);
        float eb = expf(btl);  // one precise exp per thread per step
        float lsum = 0.f;
#pragma unroll
        for (int j = 0; j < 7; j++) {
            if (j < cntn) {
                float p = fmaf(hist[j][0], gm1[j][0], 1.0f);
                p *= fmaf(hist[j][1], gm1[j][1], 1.0f);
                p *= fmaf(hist[j][2], gm1[j][2], 1.0f);
                p *= fmaf(hist[j][3], gm1[j][3], 1.0f);
                rate[j] = Ebase[j] * p * eb;
                lsum += rate[j];
            }
        }
#pragma unroll
        for (int off = 32; off > 0; off >>= 1) lsum += __shfl_xor(lsum, off, 64);
        if (lane == 0) red[s & 1][wid] = lsum;
        __syncthreads();
        const float4* r4 = (const float4*)red[s & 1];
        float4 q0 = r4[0], q1 = r4[1], q2 = r4[2], q3 = r4[3];
        float tsum = ((q0.x + q0.y) + (q0.z + q0.w)) + ((q1.x + q1.y) + (q1.z + q1.w)) +
                     ((q2.x + q2.y) + (q2.z + q2.w)) + ((q3.x + q3.y) + (q3.z + q3.w));
        float thr = tsum * (1.0f / (float)TOT);
#pragma unroll
        for (int j = 0; j < 7; j++) {
            if (j < cntn) {
                float sp = (rate[j] > thr) ? 1.0f : 0.0f;
                cnt[j] += sp;
                hist[j][0] = hist[j][1];
                hist[j][1] = hist[j][2];
                hist[j][2] = hist[j][3];
                hist[j][3] = sp;
            }
        }
        // next step writes red[(s+1)&1] — different buffer, no second barrier needed
    }

#pragma unroll
    for (int j = 0; j < 7; j++) {
        if (j < cntn) {
            float c = cnt[j];
            out[b * NEUR + n0 + j] = c + log1pf(expf(-c));
        }
    }
}

extern "C" void kernel_launch(void* const* d_in, const int* in_sizes, int n_in,
                              void* d_out, int out_size, void* d_ws, size_t ws_size,
                              hipStream_t stream) {
    const float* x = (const float*)d_in[0];
    const float* l_weight = (const float*)d_in[1];
    const float* h_weight = (const float*)d_in[2];
    const float* fc_w = (const float*)d_in[3];
    const float* fc_b = (const float*)d_in[4];
    float* out = (float*)d_out;

    float* xf_part = (float*)d_ws;  // [4][128][64] = 131,072 B

    poolfc_kernel<<<BATCH * NQ, 512, 0, stream>>>(x, fc_w, xf_part);
    recurrence_kernel<<<1, RTPB, 0, stream>>>(xf_part, fc_b, l_weight, h_weight, out);
}

// Round 4
// 343.599 us; speedup vs baseline: 1.0540x; 1.0540x over previous
//
#include <hip/hip_runtime.h>
#include <hip/hip_bf16.h>
#include <math.h>

#define BATCH 128
#define NEUR 54
#define DT 4
#define STEPS 30
#define PDIM 75             // pooled spatial dim
#define K (PDIM * PDIM)     // 5625
#define QK 1408             // quarter-K padded to 22*64; q=3 covers only 1401
#define NQ 4
#define TOT (BATCH * NEUR)  // 6912
#define RTPB 1024

// ---------------- Kernel 1 (fused): pool quarter-row into LDS, then partial FC -----
// REVERTED to the round-0 best-measured configuration (343.7 us). Rounds 1-3 showed
// all kernel-side deltas (K2 -30% instrs, K1 occupancy/NT restructure) land within
// the +-2.7% machine-noise band measured on the harness's own fill kernels
// (105.4-110.1 us drift) -> lock in the best-measured config.
// grid = 512 blocks: block = (batch b, quarter q). 1024 threads, 2 blocks/CU so the
// HBM-bound pool phase of one block overlaps the L2/VALU-bound FC phase of its
// co-resident neighbor.
__global__ __launch_bounds__(1024) void poolfc_kernel(const float* __restrict__ x,
                                                      const float* __restrict__ fc_w,
                                                      float* __restrict__ xf_part) {
    __shared__ float xps[QK];
    int blk = blockIdx.x;
    int b = blk >> 2;
    int q = blk & 3;
    int tid = threadIdx.x;
    int kbase = q * QK;
    int cnt = (q == 3) ? (K - 3 * QK) : QK;  // 1401 or 1408
    const float* xrow = x + (size_t)b * 360000;

    // ---- pool phase: avg_pool2d(x,8) for this quarter -> LDS (tail zeroed) ----
    for (int w = tid; w < QK; w += 1024) {
        float s = 0.f;
        if (w < cnt) {
            int gw = kbase + w;
            int i = gw / PDIM;
            int j = gw - i * PDIM;
            const float* base = xrow + (size_t)(i * 8) * 600 + j * 8;
#pragma unroll
            for (int r = 0; r < 8; r++) {
                const float4* p4 = (const float4*)(base + r * 600);
                float4 a = p4[0];
                float4 c = p4[1];
                s += a.x + a.y + a.z + a.w + c.x + c.y + c.z + c.w;
            }
            s *= (1.0f / 64.0f);
        }
        xps[w] = s;
    }
    __syncthreads();

    // ---- FC phase: wave w -> neurons 4w..4w+3, k on lanes (coalesced fc_w reads) ----
    int wid = tid >> 6, lane = tid & 63;
    int nb = wid * 4;  // waves 0..13 active, 14/15 idle
    if (nb < NEUR) {
        int v1 = (nb + 1 < NEUR), v2 = (nb + 2 < NEUR), v3 = (nb + 3 < NEUR);
        int n1 = v1 ? nb + 1 : nb;
        int n2 = v2 ? nb + 2 : nb;
        int n3 = v3 ? nb + 3 : nb;
        const float* p0 = fc_w + (size_t)nb * K + kbase;
        const float* p1 = fc_w + (size_t)n1 * K + kbase;
        const float* p2 = fc_w + (size_t)n2 * K + kbase;
        const float* p3 = fc_w + (size_t)n3 * K + kbase;
        float a0 = 0.f, a1 = 0.f, a2 = 0.f, a3 = 0.f;
        int full = (cnt == QK) ? (QK / 64) : (QK / 64 - 1);  // unguarded chunks
        for (int c = 0; c < full; c++) {
            int kk = c * 64 + lane;
            float xv = xps[kk];
            a0 += xv * p0[kk];
            a1 += xv * p1[kk];
            a2 += xv * p2[kk];
            a3 += xv * p3[kk];
        }
        if (cnt != QK) {  // guarded tail chunk (q==3 only)
            int kk = (QK / 64 - 1) * 64 + lane;
            if (kk < cnt) {
                float xv = xps[kk];
                a0 += xv * p0[kk];
                a1 += xv * p1[kk];
                a2 += xv * p2[kk];
                a3 += xv * p3[kk];
            }
        }
#pragma unroll
        for (int off = 32; off > 0; off >>= 1) {
            a0 += __shfl_xor(a0, off, 64);
            a1 += __shfl_xor(a1, off, 64);
            a2 += __shfl_xor(a2, off, 64);
            a3 += __shfl_xor(a3, off, 64);
        }
        if (lane == 0) {
            float* dst = xf_part + (size_t)q * (BATCH * 64) + b * 64 + nb;
            dst[0] = a0;
            if (v1) dst[1] = a1;
            if (v2) dst[2] = a2;
            if (v3) dst[3] = a3;
        }
    }
}

// ---------------- Kernel 2: 30-step GLM recurrence, single block --------------------
// 8 threads per batch (8*128 = 1024), <=7 neurons/thread. Per-batch lateral total via
// segmented shfl_xor(8); global mean via wave tree -> 16 LDS partials (double-
// buffered, 1 barrier/step, float4 readback). Round-0 form (best measured).
__global__ __launch_bounds__(RTPB) void recurrence_kernel(const float* __restrict__ xf_part,
                                                          const float* __restrict__ fc_b,
                                                          const float* __restrict__ l_weight,
                                                          const float* __restrict__ h_weight,
                                                          float* __restrict__ out) {
    __shared__ float red[2][16];

    int tid = threadIdx.x;
    int b = tid >> 3;
    int sub = tid & 7;
    int n0 = sub * 7;
    int cntn = NEUR - n0; if (cntn > 7) cntn = 7; if (cntn < 0) cntn = 0;  // sub=7 -> 5

    float hw0 = h_weight[0], hw1 = h_weight[1], hw2 = h_weight[2], hw3 = h_weight[3];

    float hist[7][DT];
    float lw[7][DT];
    float xfv[7], cnt[7], rate[7];

#pragma unroll
    for (int j = 0; j < 7; j++) {
        cnt[j] = 0.f;
#pragma unroll
        for (int d = 0; d < DT; d++) hist[j][d] = 0.f;
        if (j < cntn) {
            int n = n0 + j;
            xfv[j] = xf_part[b * 64 + n] + xf_part[BATCH * 64 + b * 64 + n] +
                     xf_part[2 * BATCH * 64 + b * 64 + n] +
                     xf_part[3 * BATCH * 64 + b * 64 + n] + fc_b[n];
#pragma unroll
            for (int d = 0; d < DT; d++) lw[j][d] = l_weight[n * DT + d];
        } else {
            xfv[j] = 0.f;
#pragma unroll
            for (int d = 0; d < DT; d++) lw[j][d] = 0.f;
        }
    }

    int wid = tid >> 6;  // 16 waves
    int lane = tid & 63;

    for (int s = 0; s < STEPS; s++) {
        float hsum[7];
        float btl = 0.f;
#pragma unroll
        for (int j = 0; j < 7; j++) {
            hsum[j] = hist[j][0] * lw[j][0] + hist[j][1] * lw[j][1] +
                      hist[j][2] * lw[j][2] + hist[j][3] * lw[j][3];
            btl += hsum[j];
        }
#pragma unroll
        for (int off = 4; off > 0; off >>= 1) btl += __shfl_xor(btl, off, 8);
        float lsum = 0.f;
#pragma unroll
        for (int j = 0; j < 7; j++) {
            if (j < cntn) {
                float hterm = hist[j][0] * hw0 + hist[j][1] * hw1 +
                              hist[j][2] * hw2 + hist[j][3] * hw3;
                float cur = xfv[j] + (btl - hsum[j]) + hterm;
                rate[j] = expf(cur);
                lsum += rate[j];
            }
        }
#pragma unroll
        for (int off = 32; off > 0; off >>= 1) lsum += __shfl_xor(lsum, off, 64);
        if (lane == 0) red[s & 1][wid] = lsum;
        __syncthreads();
        const float4* r4 = (const float4*)red[s & 1];
        float4 q0 = r4[0], q1 = r4[1], q2 = r4[2], q3 = r4[3];
        float tsum = ((q0.x + q0.y) + (q0.z + q0.w)) + ((q1.x + q1.y) + (q1.z + q1.w)) +
                     ((q2.x + q2.y) + (q2.z + q2.w)) + ((q3.x + q3.y) + (q3.z + q3.w));
        float thr = tsum * (1.0f / (float)TOT);
#pragma unroll
        for (int j = 0; j < 7; j++) {
            if (j < cntn) {
                float sp = (rate[j] > thr) ? 1.0f : 0.0f;
                cnt[j] += sp;
                hist[j][0] = hist[j][1];
                hist[j][1] = hist[j][2];
                hist[j][2] = hist[j][3];
                hist[j][3] = sp;
            }
        }
        // next step writes red[(s+1)&1] — different buffer, no second barrier needed
    }

#pragma unroll
    for (int j = 0; j < 7; j++) {
        if (j < cntn) {
            float c = cnt[j];
            out[b * NEUR + n0 + j] = c + log1pf(expf(-c));
        }
    }
}

extern "C" void kernel_launch(void* const* d_in, const int* in_sizes, int n_in,
                              void* d_out, int out_size, void* d_ws, size_t ws_size,
                              hipStream_t stream) {
    const float* x = (const float*)d_in[0];
    const float* l_weight = (const float*)d_in[1];
    const float* h_weight = (const float*)d_in[2];
    const float* fc_w = (const float*)d_in[3];
    const float* fc_b = (const float*)d_in[4];
    float* out = (float*)d_out;

    float* xf_part = (float*)d_ws;  // [4][128][64] = 131,072 B

    poolfc_kernel<<<BATCH * NQ, 1024, 0, stream>>>(x, fc_w, xf_part);
    recurrence_kernel<<<1, RTPB, 0, stream>>>(xf_part, fc_b, l_weight, h_weight, out);
}

// Round 5
// 340.657 us; speedup vs baseline: 1.0631x; 1.0086x over previous
//
#include <hip/hip_runtime.h>
#include <hip/hip_bf16.h>
#include <math.h>

#define BATCH 128
#define NEUR 54
#define DT 4
#define STEPS 30
#define PDIM 75             // pooled spatial dim
#define K (PDIM * PDIM)     // 5625
#define QK 1408             // quarter-K padded to 22*64; q=3 covers only 1401
#define NQ 4
#define TOT (BATCH * NEUR)  // 6912
#define RTPB 1024

// ---------------- Kernel 1a: pool quarter-row -> workspace ------------------------
// Split from the fused poolfc (R5): pure 184 MB x-stream, no FC phase competing for
// L2. Block = (batch b, quarter q), 1024 threads — indexing/summation order bitwise
// identical to the fused pool phase (incl. zeroed tail), dest is ws instead of LDS.
__global__ __launch_bounds__(1024) void pool_kernel(const float* __restrict__ x,
                                                    float* __restrict__ pooled) {
    int blk = blockIdx.x;
    int b = blk >> 2;
    int q = blk & 3;
    int tid = threadIdx.x;
    int kbase = q * QK;
    int cnt = (q == 3) ? (K - 3 * QK) : QK;  // 1401 or 1408
    const float* xrow = x + (size_t)b * 360000;

    for (int w = tid; w < QK; w += 1024) {
        float s = 0.f;
        if (w < cnt) {
            int gw = kbase + w;
            int i = gw / PDIM;
            int j = gw - i * PDIM;
            const float* base = xrow + (size_t)(i * 8) * 600 + j * 8;
#pragma unroll
            for (int r = 0; r < 8; r++) {
                const float4* p4 = (const float4*)(base + r * 600);
                float4 a = p4[0];
                float4 c = p4[1];
                s += a.x + a.y + a.z + a.w + c.x + c.y + c.z + c.w;
            }
            s *= (1.0f / 64.0f);
        }
        pooled[(size_t)blk * QK + w] = s;  // tail zeros for q==3, same as LDS version
    }
}

// ---------------- Kernel 1b: FC from L2-resident pooled ---------------------------
// Runs after the x-stream is fully drained: pooled (2.9 MB) + fc_w (1.2 MB) are
// L2-resident, no eviction pressure. Stage quarter-row ws->LDS, then the FC phase
// is byte-identical to the fused version (same kk order, same shfl tree) -> xf_part
// bitwise unchanged.
__global__ __launch_bounds__(1024) void fc_kernel(const float* __restrict__ pooled,
                                                  const float* __restrict__ fc_w,
                                                  float* __restrict__ xf_part) {
    __shared__ float xps[QK];
    int blk = blockIdx.x;
    int b = blk >> 2;
    int q = blk & 3;
    int tid = threadIdx.x;
    int kbase = q * QK;
    int cnt = (q == 3) ? (K - 3 * QK) : QK;

    for (int w = tid; w < QK; w += 1024) xps[w] = pooled[(size_t)blk * QK + w];
    __syncthreads();

    // ---- FC phase: wave w -> neurons 4w..4w+3, k on lanes (coalesced fc_w reads) ----
    int wid = tid >> 6, lane = tid & 63;
    int nb = wid * 4;  // waves 0..13 active, 14/15 idle
    if (nb < NEUR) {
        int v1 = (nb + 1 < NEUR), v2 = (nb + 2 < NEUR), v3 = (nb + 3 < NEUR);
        int n1 = v1 ? nb + 1 : nb;
        int n2 = v2 ? nb + 2 : nb;
        int n3 = v3 ? nb + 3 : nb;
        const float* p0 = fc_w + (size_t)nb * K + kbase;
        const float* p1 = fc_w + (size_t)n1 * K + kbase;
        const float* p2 = fc_w + (size_t)n2 * K + kbase;
        const float* p3 = fc_w + (size_t)n3 * K + kbase;
        float a0 = 0.f, a1 = 0.f, a2 = 0.f, a3 = 0.f;
        int full = (cnt == QK) ? (QK / 64) : (QK / 64 - 1);  // unguarded chunks
        for (int c = 0; c < full; c++) {
            int kk = c * 64 + lane;
            float xv = xps[kk];
            a0 += xv * p0[kk];
            a1 += xv * p1[kk];
            a2 += xv * p2[kk];
            a3 += xv * p3[kk];
        }
        if (cnt != QK) {  // guarded tail chunk (q==3 only)
            int kk = (QK / 64 - 1) * 64 + lane;
            if (kk < cnt) {
                float xv = xps[kk];
                a0 += xv * p0[kk];
                a1 += xv * p1[kk];
                a2 += xv * p2[kk];
                a3 += xv * p3[kk];
            }
        }
#pragma unroll
        for (int off = 32; off > 0; off >>= 1) {
            a0 += __shfl_xor(a0, off, 64);
            a1 += __shfl_xor(a1, off, 64);
            a2 += __shfl_xor(a2, off, 64);
            a3 += __shfl_xor(a3, off, 64);
        }
        if (lane == 0) {
            float* dst = xf_part + (size_t)q * (BATCH * 64) + b * 64 + nb;
            dst[0] = a0;
            if (v1) dst[1] = a1;
            if (v2) dst[2] = a2;
            if (v3) dst[3] = a3;
        }
    }
}

// ---------------- Kernel 2: 30-step GLM recurrence, single block --------------------
// Round-0 structure (best measured; register-critical at the 128-VGPR cap — R1's
// +35-VGPR variant spilled, +14 us). Single change (R5): expf -> __expf in the hot
// loop (OCML ~14 instrs -> v_mul+v_exp, register-NEUTRAL, ~1e-7 rel perturbation;
// R1 evidence says spike decisions tolerate this).
__global__ __launch_bounds__(RTPB) void recurrence_kernel(const float* __restrict__ xf_part,
                                                          const float* __restrict__ fc_b,
                                                          const float* __restrict__ l_weight,
                                                          const float* __restrict__ h_weight,
                                                          float* __restrict__ out) {
    __shared__ float red[2][16];

    int tid = threadIdx.x;
    int b = tid >> 3;
    int sub = tid & 7;
    int n0 = sub * 7;
    int cntn = NEUR - n0; if (cntn > 7) cntn = 7; if (cntn < 0) cntn = 0;  // sub=7 -> 5

    float hw0 = h_weight[0], hw1 = h_weight[1], hw2 = h_weight[2], hw3 = h_weight[3];

    float hist[7][DT];
    float lw[7][DT];
    float xfv[7], cnt[7], rate[7];

#pragma unroll
    for (int j = 0; j < 7; j++) {
        cnt[j] = 0.f;
#pragma unroll
        for (int d = 0; d < DT; d++) hist[j][d] = 0.f;
        if (j < cntn) {
            int n = n0 + j;
            xfv[j] = xf_part[b * 64 + n] + xf_part[BATCH * 64 + b * 64 + n] +
                     xf_part[2 * BATCH * 64 + b * 64 + n] +
                     xf_part[3 * BATCH * 64 + b * 64 + n] + fc_b[n];
#pragma unroll
            for (int d = 0; d < DT; d++) lw[j][d] = l_weight[n * DT + d];
        } else {
            xfv[j] = 0.f;
#pragma unroll
            for (int d = 0; d < DT; d++) lw[j][d] = 0.f;
        }
    }

    int wid = tid >> 6;  // 16 waves
    int lane = tid & 63;

    for (int s = 0; s < STEPS; s++) {
        float hsum[7];
        float btl = 0.f;
#pragma unroll
        for (int j = 0; j < 7; j++) {
            hsum[j] = hist[j][0] * lw[j][0] + hist[j][1] * lw[j][1] +
                      hist[j][2] * lw[j][2] + hist[j][3] * lw[j][3];
            btl += hsum[j];
        }
#pragma unroll
        for (int off = 4; off > 0; off >>= 1) btl += __shfl_xor(btl, off, 8);
        float lsum = 0.f;
#pragma unroll
        for (int j = 0; j < 7; j++) {
            if (j < cntn) {
                float hterm = hist[j][0] * hw0 + hist[j][1] * hw1 +
                              hist[j][2] * hw2 + hist[j][3] * hw3;
                float cur = xfv[j] + (btl - hsum[j]) + hterm;
                rate[j] = __expf(cur);
                lsum += rate[j];
            }
        }
#pragma unroll
        for (int off = 32; off > 0; off >>= 1) lsum += __shfl_xor(lsum, off, 64);
        if (lane == 0) red[s & 1][wid] = lsum;
        __syncthreads();
        const float4* r4 = (const float4*)red[s & 1];
        float4 q0 = r4[0], q1 = r4[1], q2 = r4[2], q3 = r4[3];
        float tsum = ((q0.x + q0.y) + (q0.z + q0.w)) + ((q1.x + q1.y) + (q1.z + q1.w)) +
                     ((q2.x + q2.y) + (q2.z + q2.w)) + ((q3.x + q3.y) + (q3.z + q3.w));
        float thr = tsum * (1.0f / (float)TOT);
#pragma unroll
        for (int j = 0; j < 7; j++) {
            if (j < cntn) {
                float sp = (rate[j] > thr) ? 1.0f : 0.0f;
                cnt[j] += sp;
                hist[j][0] = hist[j][1];
                hist[j][1] = hist[j][2];
                hist[j][2] = hist[j][3];
                hist[j][3] = sp;
            }
        }
        // next step writes red[(s+1)&1] — different buffer, no second barrier needed
    }

#pragma unroll
    for (int j = 0; j < 7; j++) {
        if (j < cntn) {
            float c = cnt[j];
            out[b * NEUR + n0 + j] = c + log1pf(expf(-c));  // cold path: keep precise
        }
    }
}

extern "C" void kernel_launch(void* const* d_in, const int* in_sizes, int n_in,
                              void* d_out, int out_size, void* d_ws, size_t ws_size,
                              hipStream_t stream) {
    const float* x = (const float*)d_in[0];
    const float* l_weight = (const float*)d_in[1];
    const float* h_weight = (const float*)d_in[2];
    const float* fc_w = (const float*)d_in[3];
    const float* fc_b = (const float*)d_in[4];
    float* out = (float*)d_out;

    float* xf_part = (float*)d_ws;                  // [4][128][64] = 131,072 B
    float* pooled = xf_part + 4 * BATCH * 64;       // [512][1408] = 2,883,584 B

    pool_kernel<<<BATCH * NQ, 1024, 0, stream>>>(x, pooled);
    fc_kernel<<<BATCH * NQ, 1024, 0, stream>>>(pooled, fc_w, xf_part);
    recurrence_kernel<<<1, RTPB, 0, stream>>>(xf_part, fc_b, l_weight, h_weight, out);
}

// Round 6
// 329.494 us; speedup vs baseline: 1.0991x; 1.0339x over previous
//
#include <hip/hip_runtime.h>
#include <hip/hip_bf16.h>
#include <math.h>

#define BATCH 128
#define NEUR 54
#define DT 4
#define STEPS 30
#define PDIM 75             // pooled spatial dim
#define K (PDIM * PDIM)     // 5625
#define QK 1408             // quarter-K padded to 22*64; q=3 covers only 1401
#define NQ 4
#define TOT (BATCH * NEUR)  // 6912
#define RTPB 1024

// ---------------- Kernel 1 (fused): pool quarter-row into LDS, then partial FC -----
// R6 bisect: revert R5's pool/FC split (measured ~0 benefit; costs a 3rd launch +
// 2.9 MB HBM round-trip). This is the round-0 fused kernel, bitwise identical
// xf_part. grid = 512 blocks: block = (batch b, quarter q). 1024 threads,
// 2 blocks/CU so the HBM-bound pool phase of one block overlaps the L2/VALU-bound
// FC phase of its co-resident neighbor.
__global__ __launch_bounds__(1024) void poolfc_kernel(const float* __restrict__ x,
                                                      const float* __restrict__ fc_w,
                                                      float* __restrict__ xf_part) {
    __shared__ float xps[QK];
    int blk = blockIdx.x;
    int b = blk >> 2;
    int q = blk & 3;
    int tid = threadIdx.x;
    int kbase = q * QK;
    int cnt = (q == 3) ? (K - 3 * QK) : QK;  // 1401 or 1408
    const float* xrow = x + (size_t)b * 360000;

    // ---- pool phase: avg_pool2d(x,8) for this quarter -> LDS (tail zeroed) ----
    for (int w = tid; w < QK; w += 1024) {
        float s = 0.f;
        if (w < cnt) {
            int gw = kbase + w;
            int i = gw / PDIM;
            int j = gw - i * PDIM;
            const float* base = xrow + (size_t)(i * 8) * 600 + j * 8;
#pragma unroll
            for (int r = 0; r < 8; r++) {
                const float4* p4 = (const float4*)(base + r * 600);
                float4 a = p4[0];
                float4 c = p4[1];
                s += a.x + a.y + a.z + a.w + c.x + c.y + c.z + c.w;
            }
            s *= (1.0f / 64.0f);
        }
        xps[w] = s;
    }
    __syncthreads();

    // ---- FC phase: wave w -> neurons 4w..4w+3, k on lanes (coalesced fc_w reads) ----
    int wid = tid >> 6, lane = tid & 63;
    int nb = wid * 4;  // waves 0..13 active, 14/15 idle
    if (nb < NEUR) {
        int v1 = (nb + 1 < NEUR), v2 = (nb + 2 < NEUR), v3 = (nb + 3 < NEUR);
        int n1 = v1 ? nb + 1 : nb;
        int n2 = v2 ? nb + 2 : nb;
        int n3 = v3 ? nb + 3 : nb;
        const float* p0 = fc_w + (size_t)nb * K + kbase;
        const float* p1 = fc_w + (size_t)n1 * K + kbase;
        const float* p2 = fc_w + (size_t)n2 * K + kbase;
        const float* p3 = fc_w + (size_t)n3 * K + kbase;
        float a0 = 0.f, a1 = 0.f, a2 = 0.f, a3 = 0.f;
        int full = (cnt == QK) ? (QK / 64) : (QK / 64 - 1);  // unguarded chunks
        for (int c = 0; c < full; c++) {
            int kk = c * 64 + lane;
            float xv = xps[kk];
            a0 += xv * p0[kk];
            a1 += xv * p1[kk];
            a2 += xv * p2[kk];
            a3 += xv * p3[kk];
        }
        if (cnt != QK) {  // guarded tail chunk (q==3 only)
            int kk = (QK / 64 - 1) * 64 + lane;
            if (kk < cnt) {
                float xv = xps[kk];
                a0 += xv * p0[kk];
                a1 += xv * p1[kk];
                a2 += xv * p2[kk];
                a3 += xv * p3[kk];
            }
        }
#pragma unroll
        for (int off = 32; off > 0; off >>= 1) {
            a0 += __shfl_xor(a0, off, 64);
            a1 += __shfl_xor(a1, off, 64);
            a2 += __shfl_xor(a2, off, 64);
            a3 += __shfl_xor(a3, off, 64);
        }
        if (lane == 0) {
            float* dst = xf_part + (size_t)q * (BATCH * 64) + b * 64 + nb;
            dst[0] = a0;
            if (v1) dst[1] = a1;
            if (v2) dst[2] = a2;
            if (v3) dst[3] = a3;
        }
    }
}

// ---------------- Kernel 2: 30-step GLM recurrence, single block --------------------
// Round-0 structure (register-critical at the 128-VGPR cap — R1's +35-VGPR variant
// spilled, +14 us). Keeps R5's verified __expf in the hot loop (register-neutral,
// absmax 0.0, ~-3 us).
__global__ __launch_bounds__(RTPB) void recurrence_kernel(const float* __restrict__ xf_part,
                                                          const float* __restrict__ fc_b,
                                                          const float* __restrict__ l_weight,
                                                          const float* __restrict__ h_weight,
                                                          float* __restrict__ out) {
    __shared__ float red[2][16];

    int tid = threadIdx.x;
    int b = tid >> 3;
    int sub = tid & 7;
    int n0 = sub * 7;
    int cntn = NEUR - n0; if (cntn > 7) cntn = 7; if (cntn < 0) cntn = 0;  // sub=7 -> 5

    float hw0 = h_weight[0], hw1 = h_weight[1], hw2 = h_weight[2], hw3 = h_weight[3];

    float hist[7][DT];
    float lw[7][DT];
    float xfv[7], cnt[7], rate[7];

#pragma unroll
    for (int j = 0; j < 7; j++) {
        cnt[j] = 0.f;
#pragma unroll
        for (int d = 0; d < DT; d++) hist[j][d] = 0.f;
        if (j < cntn) {
            int n = n0 + j;
            xfv[j] = xf_part[b * 64 + n] + xf_part[BATCH * 64 + b * 64 + n] +
                     xf_part[2 * BATCH * 64 + b * 64 + n] +
                     xf_part[3 * BATCH * 64 + b * 64 + n] + fc_b[n];
#pragma unroll
            for (int d = 0; d < DT; d++) lw[j][d] = l_weight[n * DT + d];
        } else {
            xfv[j] = 0.f;
#pragma unroll
            for (int d = 0; d < DT; d++) lw[j][d] = 0.f;
        }
    }

    int wid = tid >> 6;  // 16 waves
    int lane = tid & 63;

    for (int s = 0; s < STEPS; s++) {
        float hsum[7];
        float btl = 0.f;
#pragma unroll
        for (int j = 0; j < 7; j++) {
            hsum[j] = hist[j][0] * lw[j][0] + hist[j][1] * lw[j][1] +
                      hist[j][2] * lw[j][2] + hist[j][3] * lw[j][3];
            btl += hsum[j];
        }
#pragma unroll
        for (int off = 4; off > 0; off >>= 1) btl += __shfl_xor(btl, off, 8);
        float lsum = 0.f;
#pragma unroll
        for (int j = 0; j < 7; j++) {
            if (j < cntn) {
                float hterm = hist[j][0] * hw0 + hist[j][1] * hw1 +
                              hist[j][2] * hw2 + hist[j][3] * hw3;
                float cur = xfv[j] + (btl - hsum[j]) + hterm;
                rate[j] = __expf(cur);
                lsum += rate[j];
            }
        }
#pragma unroll
        for (int off = 32; off > 0; off >>= 1) lsum += __shfl_xor(lsum, off, 64);
        if (lane == 0) red[s & 1][wid] = lsum;
        __syncthreads();
        const float4* r4 = (const float4*)red[s & 1];
        float4 q0 = r4[0], q1 = r4[1], q2 = r4[2], q3 = r4[3];
        float tsum = ((q0.x + q0.y) + (q0.z + q0.w)) + ((q1.x + q1.y) + (q1.z + q1.w)) +
                     ((q2.x + q2.y) + (q2.z + q2.w)) + ((q3.x + q3.y) + (q3.z + q3.w));
        float thr = tsum * (1.0f / (float)TOT);
#pragma unroll
        for (int j = 0; j < 7; j++) {
            if (j < cntn) {
                float sp = (rate[j] > thr) ? 1.0f : 0.0f;
                cnt[j] += sp;
                hist[j][0] = hist[j][1];
                hist[j][1] = hist[j][2];
                hist[j][2] = hist[j][3];
                hist[j][3] = sp;
            }
        }
        // next step writes red[(s+1)&1] — different buffer, no second barrier needed
    }

#pragma unroll
    for (int j = 0; j < 7; j++) {
        if (j < cntn) {
            float c = cnt[j];
            out[b * NEUR + n0 + j] = c + log1pf(expf(-c));  // cold path: keep precise
        }
    }
}

extern "C" void kernel_launch(void* const* d_in, const int* in_sizes, int n_in,
                              void* d_out, int out_size, void* d_ws, size_t ws_size,
                              hipStream_t stream) {
    const float* x = (const float*)d_in[0];
    const float* l_weight = (const float*)d_in[1];
    const float* h_weight = (const float*)d_in[2];
    const float* fc_w = (const float*)d_in[3];
    const float* fc_b = (const float*)d_in[4];
    float* out = (float*)d_out;

    float* xf_part = (float*)d_ws;  // [4][128][64] = 131,072 B

    poolfc_kernel<<<BATCH * NQ, 1024, 0, stream>>>(x, fc_w, xf_part);
    recurrence_kernel<<<1, RTPB, 0, stream>>>(xf_part, fc_b, l_weight, h_weight, out);
}